// Round 1
// baseline (162.515 us; speedup 1.0000x reference)
//
#include <hip/hip_runtime.h>
#include <hip/hip_bf16.h>

#define NN 8192
#define HH 256
#define EE (NN*32)
#define ALPHAC 0.2f
#define CHUNK 16
#define NCHUNK (NN/CHUNK)   // 512
#define CSPAD 1024

typedef __bf16 bf16x8 __attribute__((ext_vector_type(8)));
typedef float  f32x4  __attribute__((ext_vector_type(4)));

// workspace layout (float offsets)
#define OFF_WH     0
#define OFF_S      (OFF_WH + NN*HH)
#define OFF_D      (OFF_S + NN)
#define OFF_SORTD  (OFF_D + NN)
#define OFF_PERM   (OFF_SORTD + NN)            /* ints */
#define OFF_EA     (OFF_PERM + NN)
#define OFF_E1     (OFF_EA + NN)
#define OFF_SAREL  (OFF_E1 + NN)               /* intra-chunk inclusive prefix of EA */
#define OFF_SBREL  (OFF_SAREL + NN)
#define OFF_ABPART (OFF_SBREL + NN)            /* float2 x NN*HH */
#define OFF_CPAB   (OFF_ABPART + 2*NN*HH)      /* float2 x (NCHUNK+1)*HH */
#define OFF_CSA    (OFF_CPAB + 2*(NCHUNK+1)*HH)
#define OFF_CSB    (OFF_CSA + CSPAD)
#define OFF_DEG    (OFF_CSB + CSPAD)
#define OFF_V      (OFF_DEG + NN)              /* adjacent to DEG: one zero range */
#define OFF_DINV   (OFF_V + HH)
#define OFF_WNODE  (OFF_DINV + NN)
#define OFF_KEYS   (OFF_WNODE + NN)            /* u64 x NN */
#define OFF_FB16   (OFF_KEYS + 2*NN)           /* bf16 x NN*HH */
#define OFF_WT16   (OFF_FB16 + NN*HH/2)        /* bf16 x HH*HH (W_att^T) */
// total ~ 7.8M floats ~ 31 MiB

// prep: convert features->bf16, build W_att^T bf16, zero DEG+V
__global__ __launch_bounds__(256) void k_prep(const float* __restrict__ features,
                                              const float* __restrict__ W_att,
                                              float* ws) {
    int bid = blockIdx.x, tid = threadIdx.x;
    if (bid < 1024) {
        int base = (bid*256 + tid)*8;
        float4 a = *(const float4*)(features + base);
        float4 b = *(const float4*)(features + base + 4);
        bf16x8 v;
        v[0]=(__bf16)a.x; v[1]=(__bf16)a.y; v[2]=(__bf16)a.z; v[3]=(__bf16)a.w;
        v[4]=(__bf16)b.x; v[5]=(__bf16)b.y; v[6]=(__bf16)b.z; v[7]=(__bf16)b.w;
        *(bf16x8*)((__bf16*)(ws + OFF_FB16) + base) = v;
    } else if (bid < 1056) {
        int idx0 = ((bid-1024)*256 + tid)*8;
        __bf16* WT = (__bf16*)(ws + OFF_WT16);
        #pragma unroll
        for (int q = 0; q < 8; ++q) {
            int idx = idx0 + q;
            int n = idx >> 8, k = idx & 255;
            WT[idx] = (__bf16)W_att[(size_t)k*HH + n];
        }
    } else {
        int z0 = ((bid-1056)*256 + tid)*8;
        #pragma unroll
        for (int q = 0; q < 8; ++q) {
            int i = z0 + q;
            if (i < NN + HH) ws[OFF_DEG + i] = 0.f;
        }
    }
}

// Wh = features @ W_att via MFMA bf16 (f32 accum, direct frag loads, no LDS)
// + fused k_deg (blocks 512..1535)
__global__ __launch_bounds__(256) void k_gemm_deg(const int* __restrict__ ei, float* ws) {
    int bid = blockIdx.x, tid = threadIdx.x;
    if (bid < 512) {
        int mt = bid >> 2, nt = bid & 3;
        int wave = tid >> 6, lane = tid & 63;
        int ml = lane & 15, quad = lane >> 4;
        int row0 = mt*64 + wave*16;
        int n0 = nt*64;
        const __bf16* FB = (const __bf16*)(ws + OFF_FB16);
        const __bf16* WT = (const __bf16*)(ws + OFF_WT16);
        const __bf16* Ap = FB + (size_t)(row0 + ml)*HH + quad*8;
        const __bf16* B0 = WT + (size_t)(n0 +  0 + ml)*HH + quad*8;
        const __bf16* B1 = WT + (size_t)(n0 + 16 + ml)*HH + quad*8;
        const __bf16* B2 = WT + (size_t)(n0 + 32 + ml)*HH + quad*8;
        const __bf16* B3 = WT + (size_t)(n0 + 48 + ml)*HH + quad*8;
        f32x4 ac0 = {0.f,0.f,0.f,0.f}, ac1 = ac0, ac2 = ac0, ac3 = ac0;
        #pragma unroll
        for (int k0 = 0; k0 < HH; k0 += 32) {
            bf16x8 af = *(const bf16x8*)(Ap + k0);
            ac0 = __builtin_amdgcn_mfma_f32_16x16x32_bf16(af, *(const bf16x8*)(B0 + k0), ac0, 0, 0, 0);
            ac1 = __builtin_amdgcn_mfma_f32_16x16x32_bf16(af, *(const bf16x8*)(B1 + k0), ac1, 0, 0, 0);
            ac2 = __builtin_amdgcn_mfma_f32_16x16x32_bf16(af, *(const bf16x8*)(B2 + k0), ac2, 0, 0, 0);
            ac3 = __builtin_amdgcn_mfma_f32_16x16x32_bf16(af, *(const bf16x8*)(B3 + k0), ac3, 0, 0, 0);
        }
        float* Whp = ws + OFF_WH;
        #pragma unroll
        for (int r = 0; r < 4; ++r) {
            size_t grow = (size_t)(row0 + quad*4 + r)*HH + n0 + ml;
            Whp[grow +  0] = ac0[r];
            Whp[grow + 16] = ac1[r];
            Whp[grow + 32] = ac2[r];
            Whp[grow + 48] = ac3[r];
        }
    } else {
        int e = (bid - 512)*256 + tid;
        atomicAdd(ws + OFF_DEG + ei[e], 1.0f);
    }
}

// s_i, d_i + sortable u64 key (blocks < 2048); dinv/wnode-init (blocks 2048..2079)
__global__ __launch_bounds__(256) void k_sd_dinv2(const float* __restrict__ a_src,
                                                  const float* __restrict__ a_dst,
                                                  float* ws) {
    int bid = blockIdx.x, tid = threadIdx.x;
    if (bid < 2048) {
        int wave = tid >> 6, lane = tid & 63;
        int row = bid*4 + wave;
        const float* Wh = ws + OFF_WH;
        float4 wh = *(const float4*)(Wh + (size_t)row*HH + lane*4);
        float4 as = *(const float4*)(a_src + lane*4);
        float4 ad = *(const float4*)(a_dst + lane*4);
        float ss = wh.x*as.x + wh.y*as.y + wh.z*as.z + wh.w*as.w;
        float dd = wh.x*ad.x + wh.y*ad.y + wh.z*ad.z + wh.w*ad.w;
        #pragma unroll
        for (int off = 32; off; off >>= 1) {
            ss += __shfl_xor(ss, off);
            dd += __shfl_xor(dd, off);
        }
        if (lane == 0) {
            ws[OFF_S+row] = ss; ws[OFF_D+row] = dd;
            unsigned u = __float_as_uint(dd);
            unsigned mono = u ^ ((u & 0x80000000u) ? 0xFFFFFFFFu : 0x80000000u);
            ((unsigned long long*)(ws + OFF_KEYS))[row] =
                (((unsigned long long)mono) << 13) | (unsigned)row;
        }
    } else {
        int i = (bid - 2048)*256 + tid;
        float dv = rsqrtf(ws[OFF_DEG + i] + 1.0f);   // +1 = self-loop
        ws[OFF_DINV + i] = dv;
        ws[OFF_WNODE + i] = dv*dv;                   // self-loop term
    }
}

// rank by counting with u64 keys (branchless v_cmp_lt_u64)
__global__ __launch_bounds__(256) void k_rank(float* ws) {
    __shared__ unsigned long long lk[NN];   // 64 KB
    const unsigned long long* keys = (const unsigned long long*)(ws + OFF_KEYS);
    int tid = threadIdx.x;
    for (int m = tid; m < NN/2; m += 256)
        *(ulonglong2*)&lk[m*2] = *(const ulonglong2*)&keys[m*2];
    __syncthreads();
    int wave = tid >> 6, lane = tid & 63;
    int jb = blockIdx.x*16 + wave*4;
    unsigned long long kj0 = lk[jb+0], kj1 = lk[jb+1];
    unsigned long long kj2 = lk[jb+2], kj3 = lk[jb+3];
    int c0 = 0, c1 = 0, c2 = 0, c3 = 0;
    #pragma unroll 4
    for (int it = 0; it < 64; ++it) {
        ulonglong2 kq = *(const ulonglong2*)&lk[(it*64 + lane)*2];
        c0 += (kq.x < kj0); c1 += (kq.x < kj1);
        c2 += (kq.x < kj2); c3 += (kq.x < kj3);
        c0 += (kq.y < kj0); c1 += (kq.y < kj1);
        c2 += (kq.y < kj2); c3 += (kq.y < kj3);
    }
    #pragma unroll
    for (int off = 1; off < 64; off <<= 1) {
        c0 += __shfl_xor(c0, off);
        c1 += __shfl_xor(c1, off);
        c2 += __shfl_xor(c2, off);
        c3 += __shfl_xor(c3, off);
    }
    if (lane == 0) {
        unsigned long long kk[4] = {kj0, kj1, kj2, kj3};
        int cr[4] = {c0, c1, c2, c3};
        #pragma unroll
        for (int q = 0; q < 4; ++q) {
            unsigned long long kv = kk[q];
            int r = cr[q];
            unsigned mm = (unsigned)(kv >> 13);
            unsigned u = (mm & 0x80000000u) ? (mm ^ 0x80000000u) : ~mm;
            float dj = __uint_as_float(u);
            int j = (int)(kv & 8191ULL);
            ws[OFF_SORTD + r] = dj;
            ((int*)ws)[OFF_PERM + r] = j;
            ws[OFF_EA + r] = expf(ALPHAC * dj);
            ws[OFF_E1 + r] = expf(dj);
        }
    }
}

// vecpref (blocks < NCHUNK): per-chunk(16) vector prefixes (float2-interleaved)
// + intra-chunk scalar prefixes + chunk totals. wnode (blocks NCHUNK..NCHUNK+1023).
__global__ __launch_bounds__(256) void k_wnode_vecpref(const int* __restrict__ ei, float* ws) {
    int bid = blockIdx.x, tid = threadIdx.x;
    if (bid < NCHUNK) {
        __shared__ int   sp[CHUNK];
        __shared__ float sea[CHUNK], se1[CHUNK];
        int c = bid, h = tid;
        int k0 = c * CHUNK;
        if (h < CHUNK) {
            sp[h]  = ((int*)ws)[OFF_PERM + k0 + h];
            sea[h] = ws[OFF_EA + k0 + h];
            se1[h] = ws[OFF_E1 + k0 + h];
        }
        __syncthreads();
        if (tid < 64) {   // wave 0: scalar intra-chunk scans via shfl
            int lane = tid;
            float v = 0.f;
            if (lane < 16) v = sea[lane];
            else if (lane < 32) v = se1[lane-16];
            #pragma unroll
            for (int off = 1; off < 16; off <<= 1) {
                float x = __shfl_up(v, off);
                if ((lane & 15) >= off) v += x;
            }
            if (lane < 16) {
                ws[OFF_SAREL + k0 + lane] = v;
                if (lane == 15) ws[OFF_CSA + c + 1] = v;
            } else if (lane < 32) {
                ws[OFF_SBREL + k0 + lane - 16] = v;
                if (lane == 31) ws[OFF_CSB + c + 1] = v;
            }
        }
        const float* Wh = ws + OFF_WH;
        float wv[CHUNK];
        #pragma unroll
        for (int kk = 0; kk < CHUNK; ++kk)
            wv[kk] = Wh[(size_t)sp[kk]*HH + h];
        float2* abp = (float2*)(ws + OFF_ABPART);
        float acca = 0.f, accb = 0.f;
        #pragma unroll
        for (int kk = 0; kk < CHUNK; ++kk) {
            acca += sea[kk]*wv[kk]; accb += se1[kk]*wv[kk];
            abp[(size_t)(k0+kk)*HH + h] = make_float2(acca, accb);
        }
        float2* cp = (float2*)(ws + OFF_CPAB);
        cp[(size_t)(c+1)*HH + h] = make_float2(acca, accb);
    } else {
        int e = (bid - NCHUNK)*256 + tid;
        int r = ei[e], cix = ei[EE + e];
        atomicAdd(ws + OFF_WNODE + cix, ws[OFF_DINV + r] * ws[OFF_DINV + cix]);
    }
}

// in-place exclusive scan of chunk totals (blocks 0..31: vector float2; block 32: scalars)
__global__ __launch_bounds__(256) void k_chunkscan(float* ws) {
    int bid = blockIdx.x, tid = threadIdx.x;
    if (bid < 32) {
        int h = bid*8 + (tid >> 5);
        int t = tid & 31;
        float2* cp = (float2*)(ws + OFF_CPAB);
        float la[16], lb[16];
        float ta = 0.f, tb = 0.f;
        #pragma unroll
        for (int m = 0; m < 16; ++m) {
            float2 v = cp[(size_t)(t*16 + m + 1)*HH + h];
            la[m] = v.x; lb[m] = v.y;
            ta += la[m]; tb += lb[m];
        }
        float ia = ta, ib = tb;
        #pragma unroll
        for (int off = 1; off < 32; off <<= 1) {
            float xa = __shfl_up(ia, off, 32);
            float xb = __shfl_up(ib, off, 32);
            if (t >= off) { ia += xa; ib += xb; }
        }
        float ba = ia - ta, bb = ib - tb;
        __syncthreads();
        #pragma unroll
        for (int m = 0; m < 16; ++m) {
            cp[(size_t)(t*16 + m)*HH + h] = make_float2(ba, bb);
            ba += la[m]; bb += lb[m];
        }
        if (t == 31) cp[(size_t)NCHUNK*HH + h] = make_float2(ba, bb);
    } else {
        int lane = tid & 63, wvi = tid >> 6;
        bool act = wvi < 2;
        float* cs = ws + (wvi == 1 ? OFF_CSB : OFF_CSA);
        float la[8];
        float ta = 0.f;
        if (act) {
            #pragma unroll
            for (int m = 0; m < 8; ++m) { la[m] = cs[lane*8 + m + 1]; ta += la[m]; }
        }
        float ia = ta;
        #pragma unroll
        for (int off = 1; off < 64; off <<= 1) {
            float x = __shfl_up(ia, off);
            if (lane >= off) ia += x;
        }
        float ba = ia - ta;
        __syncthreads();
        if (act) {
            #pragma unroll
            for (int m = 0; m < 8; ++m) { cs[lane*8 + m] = ba; ba += la[m]; }
            if (lane == 63) cs[NCHUNK] = ba;
        }
    }
}

__device__ __forceinline__ float elu1(float x) {
    return x > 0.f ? x : (expf(x) - 1.f);
}

// per-row attention via prefix lookup; accumulate v = sum_i wnode[i]*h1[i]
__global__ __launch_bounds__(256) void k_rows(float* ws) {
    __shared__ float sd[NN];       // 32 KB sorted d
    __shared__ float red[4][256];
    int tid = threadIdx.x;
    for (int m = tid; m < NN/4; m += 256)
        *(float4*)&sd[m*4] = *(const float4*)(ws + OFF_SORTD + m*4);
    __syncthreads();
    int wave = tid >> 6, lane = tid & 63;
    int gw = blockIdx.x*4 + wave;            // 0..2047
    const float2* abp  = (const float2*)(ws + OFF_ABPART);
    const float2* cpab = (const float2*)(ws + OFF_CPAB);
    float btot = ws[OFF_CSB + NCHUNK];
    const float4* btr = (const float4*)(cpab + (size_t)NCHUNK*HH);
    float4 bt0 = btr[lane*2], bt1 = btr[lane*2+1];
    float BTx = bt0.y, BTy = bt0.w, BTz = bt1.y, BTw = bt1.w;

    int myr = lane & 3;
    float si_m = ws[OFF_S + gw*4 + myr];
    float tt = -si_m;
    int lo = 0, hi = NN;
    while (lo < hi) {
        int mid = (lo + hi) >> 1;
        if (sd[mid] <= tt) lo = mid + 1; else hi = mid;
    }

    float accx = 0.f, accy = 0.f, accz = 0.f, accw = 0.f;
    #pragma unroll
    for (int r = 0; r < 4; ++r) {
        int i = gw*4 + r;
        int k = __shfl(lo, r);
        float si = __shfl(si_m, r);
        float eas = expf(ALPHAC * si), es = expf(si);
        float av = 0.f, bv = 0.f;
        float Ax=0.f, Ay=0.f, Az=0.f, Aw=0.f, Bx=0.f, By=0.f, Bz=0.f, Bw=0.f;
        if (k > 0) {
            int km = k - 1, cc = km >> 4;
            av = ws[OFF_CSA + cc] + ws[OFF_SAREL + km];
            bv = ws[OFF_CSB + cc] + ws[OFF_SBREL + km];
            const float4* pr = (const float4*)(abp + (size_t)km*HH);
            const float4* cr = (const float4*)(cpab + (size_t)cc*HH);
            float4 p0 = pr[lane*2], p1 = pr[lane*2+1];
            float4 q0 = cr[lane*2], q1 = cr[lane*2+1];
            Ax = p0.x + q0.x; Bx = p0.y + q0.y;
            Ay = p0.z + q0.z; By = p0.w + q0.w;
            Az = p1.x + q1.x; Bz = p1.y + q1.y;
            Aw = p1.z + q1.z; Bw = p1.w + q1.w;
        }
        float Z = eas*av + es*(btot - bv);
        float invZ = 1.f / Z;
        float w = ws[OFF_WNODE + i];
        accx += w * elu1((eas*Ax + es*(BTx - Bx)) * invZ);
        accy += w * elu1((eas*Ay + es*(BTy - By)) * invZ);
        accz += w * elu1((eas*Az + es*(BTz - Bz)) * invZ);
        accw += w * elu1((eas*Aw + es*(BTw - Bw)) * invZ);
    }
    red[wave][lane*4+0] = accx;
    red[wave][lane*4+1] = accy;
    red[wave][lane*4+2] = accz;
    red[wave][lane*4+3] = accw;
    __syncthreads();
    float sum = red[0][tid] + red[1][tid] + red[2][tid] + red[3][tid];
    atomicAdd(ws + OFF_V + tid, sum);
}

// head: (v @ gcn_w)/N + gcn_b -> @ out_w + out_b -> softmax(2)
__global__ void k_final(const float* __restrict__ gcn_w, const float* __restrict__ gcn_b,
                        const float* __restrict__ out_w, const float* __restrict__ out_b,
                        float* ws, float* out) {
    __shared__ float vl[HH];
    __shared__ float r0s[256], r1s[256];
    int t = threadIdx.x;
    vl[t] = ws[OFF_V + t];
    __syncthreads();
    float acc = 0.f;
    for (int h = 0; h < HH; ++h) acc += vl[h] * gcn_w[(size_t)h*HH + t];
    float meanv = acc * (1.0f/(float)NN) + gcn_b[t];
    r0s[t] = meanv * out_w[t*2+0];
    r1s[t] = meanv * out_w[t*2+1];
    __syncthreads();
    for (int off = 128; off; off >>= 1) {
        if (t < off) { r0s[t] += r0s[t+off]; r1s[t] += r1s[t+off]; }
        __syncthreads();
    }
    if (t == 0) {
        float res0 = r0s[0] + out_b[0], res1 = r1s[0] + out_b[1];
        float m = fmaxf(res0, res1);
        float e0 = expf(res0 - m), e1v = expf(res1 - m);
        float inv = 1.f / (e0 + e1v);
        out[0] = e0 * inv;
        out[1] = e1v * inv;
    }
}

extern "C" void kernel_launch(void* const* d_in, const int* in_sizes, int n_in,
                              void* d_out, int out_size, void* d_ws, size_t ws_size,
                              hipStream_t stream) {
    const float* features = (const float*)d_in[0];
    const int*   eidx     = (const int*)d_in[1];
    const float* W_att    = (const float*)d_in[2];
    const float* a_src    = (const float*)d_in[3];
    const float* a_dst    = (const float*)d_in[4];
    const float* gcn_w    = (const float*)d_in[5];
    const float* gcn_b    = (const float*)d_in[6];
    const float* out_w    = (const float*)d_in[7];
    const float* out_b    = (const float*)d_in[8];
    float* ws  = (float*)d_ws;
    float* out = (float*)d_out;

    k_prep<<<1061, 256, 0, stream>>>(features, W_att, ws);
    k_gemm_deg<<<1536, 256, 0, stream>>>(eidx, ws);
    k_sd_dinv2<<<2080, 256, 0, stream>>>(a_src, a_dst, ws);
    k_rank<<<NN/16, 256, 0, stream>>>(ws);
    k_wnode_vecpref<<<NCHUNK + 1024, 256, 0, stream>>>(eidx, ws);
    k_chunkscan<<<33, 256, 0, stream>>>(ws);
    k_rows<<<NN/16, 256, 0, stream>>>(ws);
    k_final<<<1, 256, 0, stream>>>(gcn_w, gcn_b, out_w, out_b, ws, out);
}